// Round 1
// baseline (112.614 us; speedup 1.0000x reference)
//
#include <hip/hip_runtime.h>
#include <cstdint>
#include <cstddef>

// ---------------------------------------------------------------------------
// BasicLSTM fused kernel for MI355X (gfx950).
//   pre_g = X @ W_g + H @ U_g + b_g   for g in {f, i, o}
//   c_new = sig(pre_f)*c0 + sig(pre_f)*sig(pre_i)     (input_cell == forget!)
//   h_new = sig(pre_o)*tanh(c_new)
// Strategy: fp32 -> bf16 conversion (A row-major [M][K], weights transposed
// to [N][K]), then one fused MFMA GEMM computing all 3 gates per output tile
// with fused LSTM epilogue. m97-style: global_load_lds(16B) staging, BK=32,
// 2-barrier K-loop, 16x16x32 bf16 MFMA.
// ---------------------------------------------------------------------------

typedef __attribute__((ext_vector_type(8))) short bf16x8;
typedef __attribute__((ext_vector_type(4))) float f32x4;
typedef __attribute__((ext_vector_type(8))) short s16x8;
typedef __attribute__((ext_vector_type(4))) float f32x4v;

#define MROWS 4096
#define KDIM  1024   // D == S == 1024
#define NCOLS 1024

__device__ __forceinline__ short f2bf(float f) {
    uint32_t u = __builtin_bit_cast(uint32_t, f);
    u += 0x7fffu + ((u >> 16) & 1u);   // round-to-nearest-even
    return (short)(u >> 16);
}

// ---- fp32 -> bf16 elementwise (vectorized: 32B in / 16B out per thread) ----
__global__ void cvt_bf16_kernel(const float* __restrict__ in,
                                short* __restrict__ out, int n) {
    int i = (blockIdx.x * 256 + threadIdx.x) * 8;
    if (i >= n) return;
    f32x4v a = *(const f32x4v*)(in + i);
    f32x4v b = *(const f32x4v*)(in + i + 4);
    s16x8 o;
    o[0] = f2bf(a[0]); o[1] = f2bf(a[1]); o[2] = f2bf(a[2]); o[3] = f2bf(a[3]);
    o[4] = f2bf(b[0]); o[5] = f2bf(b[1]); o[6] = f2bf(b[2]); o[7] = f2bf(b[3]);
    *(s16x8*)(out + i) = o;
}

// ---- transpose + convert: w [K][N] fp32 -> wt [N][K] bf16 ----
__global__ void transpose_cvt_kernel(const float* __restrict__ w,
                                     short* __restrict__ wt) {
    __shared__ short tile[32][33];
    const int tx = threadIdx.x & 31;
    const int ty = threadIdx.x >> 5;          // 0..7
    const int kbase = blockIdx.y * 32;
    const int nbase = blockIdx.x * 32;
#pragma unroll
    for (int r = 0; r < 4; ++r) {
        int k = kbase + ty + r * 8;
        tile[ty + r * 8][tx] = f2bf(w[k * NCOLS + nbase + tx]);
    }
    __syncthreads();
#pragma unroll
    for (int r = 0; r < 4; ++r) {
        int n = nbase + ty + r * 8;
        wt[n * KDIM + kbase + tx] = tile[tx][ty + r * 8];
    }
}

// ---- fused 3-gate GEMM + LSTM cell ----
// Block: 512 threads = 8 waves (2 x 4 wave grid). Block tile 128x128.
// Wave tile 64x32 per gate. BK = 32. LDS: A[128][32] + 3 x B[128][32] bf16.
__global__ __launch_bounds__(512)
void lstm_gemm_kernel(const short* __restrict__ Xb, const short* __restrict__ Hb,
                      const short* __restrict__ WT0, const short* __restrict__ WT1,
                      const short* __restrict__ WT2,
                      const short* __restrict__ UT0, const short* __restrict__ UT1,
                      const short* __restrict__ UT2,
                      const float* __restrict__ bf_, const float* __restrict__ bi_,
                      const float* __restrict__ bo_,
                      const float* __restrict__ c0,
                      float* __restrict__ outH, float* __restrict__ outC) {
    __shared__ __align__(16) short lds[16384];   // 32 KB: A | B0 | B1 | B2

    const int tid  = threadIdx.x;
    const int lane = tid & 63;
    const int wave = tid >> 6;            // 0..7
    const int wm   = wave >> 2;           // 0..1  (row group)
    const int wn   = wave & 3;            // 0..3  (col group)
    const int m0   = blockIdx.y * 128;
    const int n0   = blockIdx.x * 128;

    const int l15 = lane & 15;
    const int k0b = ((lane >> 4) * 8) * 2;   // byte offset of k-chunk in 64B row

    f32x4 acc[3][4][2] = {};   // [gate][m][n] accumulators (96 VGPRs)

    // staging constants: round r covers tile r (0=A, 1..3=B gates)
    const int srow = tid >> 2;            // 0..127
    const int skb  = (tid & 3) * 16;      // byte within 64B row

    for (int kt = 0; kt < 2 * KDIM; kt += 32) {
        const short* aSrc = (kt < KDIM) ? Xb : Hb;
        const short* b0   = (kt < KDIM) ? WT0 : UT0;
        const short* b1   = (kt < KDIM) ? WT1 : UT1;
        const short* b2   = (kt < KDIM) ? WT2 : UT2;
        const int kk = kt & (KDIM - 1);

#pragma unroll
        for (int r = 0; r < 4; ++r) {
            const short* src = (r == 0) ? aSrc : (r == 1 ? b0 : (r == 2 ? b1 : b2));
            const int rbase = (r == 0) ? m0 : n0;
            const char* g = (const char*)src +
                            ((size_t)(rbase + srow) * KDIM + kk) * 2 + skb;
            const int o = tid * 16 + r * 8192;
            __builtin_amdgcn_global_load_lds(
                (const __attribute__((address_space(1))) unsigned int*)(uintptr_t)g,
                (__attribute__((address_space(3))) unsigned int*)(uintptr_t)
                    ((char*)lds + o),
                16, 0, 0);
        }
        __syncthreads();

        bf16x8 af[4];
#pragma unroll
        for (int m = 0; m < 4; ++m)
            af[m] = *(const bf16x8*)((const char*)lds +
                     ((wm * 64 + m * 16 + l15) << 6) + k0b);
#pragma unroll
        for (int g3 = 0; g3 < 3; ++g3) {
#pragma unroll
            for (int n = 0; n < 2; ++n) {
                bf16x8 bv = *(const bf16x8*)((const char*)lds + 8192 * (1 + g3) +
                             ((wn * 32 + n * 16 + l15) << 6) + k0b);
#pragma unroll
                for (int m = 0; m < 4; ++m)
                    acc[g3][m][n] = __builtin_amdgcn_mfma_f32_16x16x32_bf16(
                        af[m], bv, acc[g3][m][n], 0, 0, 0);
            }
        }
        __syncthreads();
    }

    // ---- fused LSTM epilogue ----
    const int rj = (lane >> 4) * 4;   // row sub-offset within 16x16 frag
#pragma unroll
    for (int m = 0; m < 4; ++m) {
#pragma unroll
        for (int n = 0; n < 2; ++n) {
            const int col = n0 + wn * 32 + n * 16 + l15;
            const float bfv = bf_[col], biv = bi_[col], bov = bo_[col];
            const f32x4 pf = acc[0][m][n];
            const f32x4 pi = acc[1][m][n];
            const f32x4 po = acc[2][m][n];
#pragma unroll
            for (int j = 0; j < 4; ++j) {
                const int row = m0 + wm * 64 + m * 16 + rj + j;
                const float fg = 1.f / (1.f + __expf(-(pf[j] + bfv)));
                const float ig = 1.f / (1.f + __expf(-(pi[j] + biv)));
                const float og = 1.f / (1.f + __expf(-(po[j] + bov)));
                const float cv = c0[row * NCOLS + col];
                const float cn = fg * cv + fg * ig;   // input_cell == forget gate
                const float e  = __expf(-2.f * cn);
                const float th = (1.f - e) / (1.f + e);
                outH[row * NCOLS + col] = og * th;
                outC[row * NCOLS + col] = cn;
            }
        }
    }
}

extern "C" void kernel_launch(void* const* d_in, const int* in_sizes, int n_in,
                              void* d_out, int out_size, void* d_ws, size_t ws_size,
                              hipStream_t stream) {
    const float* inputs = (const float*)d_in[0];
    const float* h0     = (const float*)d_in[1];
    const float* c0     = (const float*)d_in[2];
    const float* w_f    = (const float*)d_in[3];
    const float* u_f    = (const float*)d_in[4];
    const float* b_f    = (const float*)d_in[5];
    const float* w_i    = (const float*)d_in[6];
    const float* u_i    = (const float*)d_in[7];
    const float* b_i    = (const float*)d_in[8];
    const float* w_o    = (const float*)d_in[9];
    const float* u_o    = (const float*)d_in[10];
    const float* b_o    = (const float*)d_in[11];

    float* outH = (float*)d_out;
    float* outC = outH + (size_t)MROWS * NCOLS;

    // workspace layout (bf16):
    //   Xb  8 MB | Hb 8 MB | WT0..2 2 MB each | UT0..2 2 MB each  = 28 MB
    char* ws = (char*)d_ws;
    short* Xb  = (short*)(ws);
    short* Hb  = (short*)(ws + (8u << 20));
    short* WT0 = (short*)(ws + (16u << 20));
    short* WT1 = (short*)(ws + (18u << 20));
    short* WT2 = (short*)(ws + (20u << 20));
    short* UT0 = (short*)(ws + (22u << 20));
    short* UT1 = (short*)(ws + (24u << 20));
    short* UT2 = (short*)(ws + (26u << 20));

    const int nA = MROWS * KDIM;   // 4M elements
    cvt_bf16_kernel<<<nA / (256 * 8), 256, 0, stream>>>(inputs, Xb, nA);
    cvt_bf16_kernel<<<nA / (256 * 8), 256, 0, stream>>>(h0, Hb, nA);

    dim3 tg(32, 32);
    transpose_cvt_kernel<<<tg, 256, 0, stream>>>(w_f, WT0);
    transpose_cvt_kernel<<<tg, 256, 0, stream>>>(w_i, WT1);
    transpose_cvt_kernel<<<tg, 256, 0, stream>>>(w_o, WT2);
    transpose_cvt_kernel<<<tg, 256, 0, stream>>>(u_f, UT0);
    transpose_cvt_kernel<<<tg, 256, 0, stream>>>(u_i, UT1);
    transpose_cvt_kernel<<<tg, 256, 0, stream>>>(u_o, UT2);

    dim3 grid(NCOLS / 128, MROWS / 128);   // (8, 32) = 256 blocks
    lstm_gemm_kernel<<<grid, 512, 0, stream>>>(
        Xb, Hb, WT0, WT1, WT2, UT0, UT1, UT2,
        b_f, b_i, b_o, c0, outH, outC);
}

// Round 2
// 84.714 us; speedup vs baseline: 1.3294x; 1.3294x over previous
//
#include <hip/hip_runtime.h>
#include <cstdint>
#include <cstddef>

// ---------------------------------------------------------------------------
// BasicLSTM fused kernel for MI355X (gfx950) — round 2.
//   pre_g = X @ W_g + H @ U_g + b_g   for g in {f, i, o}
//   c_new = sig(pre_f)*c0 + sig(pre_f)*sig(pre_i)     (input_cell == forget!)
//   h_new = sig(pre_o)*tanh(c_new)
// Round-2 changes vs round 1:
//  - T3-minimum double-buffered K-loop: stage(next) issued BEFORE compute,
//    single barrier per K-step -> HBM latency hidden under MFMA+ds_read.
//  - Bank-conflict-free LDS: chunk-rotation swizzle (global-source permuted,
//    LDS dest linear per global_load_lds rules; same XOR applied on ds_read).
//  - Conversion launches fused 8 -> 2.
// ---------------------------------------------------------------------------

typedef __attribute__((ext_vector_type(8))) short bf16x8;
typedef __attribute__((ext_vector_type(4))) float f32x4;
typedef __attribute__((ext_vector_type(8))) short s16x8;
typedef __attribute__((ext_vector_type(4))) float f32x4v;

#define MROWS 4096
#define KDIM  1024   // D == S == 1024
#define NCOLS 1024

__device__ __forceinline__ short f2bf(float f) {
    uint32_t u = __builtin_bit_cast(uint32_t, f);
    u += 0x7fffu + ((u >> 16) & 1u);   // round-to-nearest-even
    return (short)(u >> 16);
}

// ---- fp32 -> bf16 for X and H in one launch (32B in / 16B out per thread) --
__global__ void cvt_bf16_kernel(const float* __restrict__ x,
                                const float* __restrict__ h,
                                short* __restrict__ xb,
                                short* __restrict__ hb) {
    int b = blockIdx.x;
    const float* in;
    short* out;
    if (b < 2048) { in = x; out = xb; }
    else          { in = h; out = hb; b -= 2048; }
    const int i = (b * 256 + threadIdx.x) * 8;
    f32x4v a = *(const f32x4v*)(in + i);
    f32x4v c = *(const f32x4v*)(in + i + 4);
    s16x8 o;
    o[0] = f2bf(a[0]); o[1] = f2bf(a[1]); o[2] = f2bf(a[2]); o[3] = f2bf(a[3]);
    o[4] = f2bf(c[0]); o[5] = f2bf(c[1]); o[6] = f2bf(c[2]); o[7] = f2bf(c[3]);
    *(s16x8*)(out + i) = o;
}

// ---- transpose + convert all 6 weights: w [K][N] fp32 -> wt [N][K] bf16 ----
struct W6 {
    const float* src[6];
    short* dst[6];
};

__global__ void transpose_cvt_kernel(W6 p) {
    __shared__ short tile[32][33];
    const float* __restrict__ w  = p.src[blockIdx.z];
    short* __restrict__       wt = p.dst[blockIdx.z];
    const int tx = threadIdx.x & 31;
    const int ty = threadIdx.x >> 5;          // 0..7
    const int kbase = blockIdx.y * 32;
    const int nbase = blockIdx.x * 32;
#pragma unroll
    for (int r = 0; r < 4; ++r) {
        int k = kbase + ty + r * 8;
        tile[ty + r * 8][tx] = f2bf(w[k * NCOLS + nbase + tx]);
    }
    __syncthreads();
#pragma unroll
    for (int r = 0; r < 4; ++r) {
        int n = nbase + ty + r * 8;
        wt[n * KDIM + kbase + tx] = tile[tx][ty + r * 8];
    }
}

// ---- fused 3-gate GEMM + LSTM cell ----
// Block: 512 threads = 8 waves (2 x 4). Block tile 128x128, 3 gates fused
// (A-tile and B-tiles shared across waves; mfma:ds_read ratio 2.4).
// BK = 32, 64 K-steps over [X|H] x [W|U]. Double-buffered 2x32KB LDS.
// LDS image per tile r (0=A,1..3=B gate): 128 rows x 4 chunks of 16B,
// chunk slot rotated by (row>>1)&3 for conflict-free ds_read_b128.
__global__ __launch_bounds__(512)
void lstm_gemm_kernel(const short* __restrict__ Xb, const short* __restrict__ Hb,
                      const short* __restrict__ WT0, const short* __restrict__ WT1,
                      const short* __restrict__ WT2,
                      const short* __restrict__ UT0, const short* __restrict__ UT1,
                      const short* __restrict__ UT2,
                      const float* __restrict__ bf_, const float* __restrict__ bi_,
                      const float* __restrict__ bo_,
                      const float* __restrict__ c0,
                      float* __restrict__ outH, float* __restrict__ outC) {
    __shared__ __align__(16) short lds[2][16384];   // 2 x 32 KB

    const int tid  = threadIdx.x;
    const int lane = tid & 63;
    const int wave = tid >> 6;            // 0..7
    const int wm   = wave >> 2;           // 0..1  (row group)
    const int wn   = wave & 3;            // 0..3  (col group)
    const int m0   = blockIdx.y * 128;
    const int n0   = blockIdx.x * 128;

    const int l15 = lane & 15;
    const int q   = lane >> 4;            // k-chunk index of this lane

    f32x4 acc[3][4][2] = {};   // [gate][m][n]

    // staging: thread tid stages LDS slot tid (16B) of each tile.
    // slot tid = row (tid>>2) chunk-slot (tid&3); it must hold global chunk
    // (tid&3) ^ ((row>>1)&3)  -> rotate the global source.
    const int srow   = tid >> 2;                       // 0..127
    const int schunk = (tid & 3) ^ ((tid >> 3) & 3);   // (tid&3)^((srow>>1)&3)
    const int skoff  = schunk * 8;                     // element offset in row

    // precomputed swizzled read byte-offsets within a tile
    int aOff[4], bOff[2];
#pragma unroll
    for (int m = 0; m < 4; ++m) {
        const int row = wm * 64 + m * 16 + l15;
        aOff[m] = row * 64 + ((q ^ ((row >> 1) & 3)) << 4);
    }
#pragma unroll
    for (int n = 0; n < 2; ++n) {
        const int row = wn * 32 + n * 16 + l15;
        bOff[n] = row * 64 + ((q ^ ((row >> 1) & 3)) << 4);
    }

    auto stage = [&](int buf, int kt) {
        const bool second = kt >= 32;
        const short* aS = second ? Hb  : Xb;
        const short* s0 = second ? UT0 : WT0;
        const short* s1 = second ? UT1 : WT1;
        const short* s2 = second ? UT2 : WT2;
        const int kk = (kt & 31) * 32 + skoff;
#pragma unroll
        for (int r = 0; r < 4; ++r) {
            const short* src = (r == 0) ? aS : (r == 1 ? s0 : (r == 2 ? s1 : s2));
            const int rbase = (r == 0) ? m0 : n0;
            const char* g = (const char*)(src + (size_t)(rbase + srow) * KDIM + kk);
            __builtin_amdgcn_global_load_lds(
                (const __attribute__((address_space(1))) unsigned int*)(uintptr_t)g,
                (__attribute__((address_space(3))) unsigned int*)(uintptr_t)
                    ((char*)&lds[buf][0] + r * 8192 + tid * 16),
                16, 0, 0);
        }
    };

    stage(0, 0);
    __syncthreads();                      // drain tile 0

    int buf = 0;
    for (int kt = 0; kt < 64; ++kt) {
        if (kt < 63) stage(buf ^ 1, kt + 1);   // issue next-tile loads FIRST

        const char* L = (const char*)&lds[buf][0];
        bf16x8 af[4];
#pragma unroll
        for (int m = 0; m < 4; ++m)
            af[m] = *(const bf16x8*)(L + aOff[m]);
#pragma unroll
        for (int g3 = 0; g3 < 3; ++g3) {
#pragma unroll
            for (int n = 0; n < 2; ++n) {
                bf16x8 bv = *(const bf16x8*)(L + 8192 * (1 + g3) + bOff[n]);
#pragma unroll
                for (int m = 0; m < 4; ++m)
                    acc[g3][m][n] = __builtin_amdgcn_mfma_f32_16x16x32_bf16(
                        af[m], bv, acc[g3][m][n], 0, 0, 0);
            }
        }
        __syncthreads();   // waits vmcnt(0): next tile landed; syncs readers
        buf ^= 1;
    }

    // ---- fused LSTM epilogue ----
    const int rj = (lane >> 4) * 4;   // row sub-offset within 16x16 frag
#pragma unroll
    for (int m = 0; m < 4; ++m) {
#pragma unroll
        for (int n = 0; n < 2; ++n) {
            const int col = n0 + wn * 32 + n * 16 + l15;
            const float bfv = bf_[col], biv = bi_[col], bov = bo_[col];
            const f32x4 pf = acc[0][m][n];
            const f32x4 pi = acc[1][m][n];
            const f32x4 po = acc[2][m][n];
#pragma unroll
            for (int j = 0; j < 4; ++j) {
                const int row = m0 + wm * 64 + m * 16 + rj + j;
                const float fg = 1.f / (1.f + __expf(-(pf[j] + bfv)));
                const float ig = 1.f / (1.f + __expf(-(pi[j] + biv)));
                const float og = 1.f / (1.f + __expf(-(po[j] + bov)));
                const float cv = c0[row * NCOLS + col];
                const float cn = fg * cv + fg * ig;   // input_cell == forget gate
                const float e  = __expf(-2.f * cn);
                const float th = (1.f - e) / (1.f + e);
                outH[row * NCOLS + col] = og * th;
                outC[row * NCOLS + col] = cn;
            }
        }
    }
}

extern "C" void kernel_launch(void* const* d_in, const int* in_sizes, int n_in,
                              void* d_out, int out_size, void* d_ws, size_t ws_size,
                              hipStream_t stream) {
    const float* inputs = (const float*)d_in[0];
    const float* h0     = (const float*)d_in[1];
    const float* c0     = (const float*)d_in[2];
    const float* w_f    = (const float*)d_in[3];
    const float* u_f    = (const float*)d_in[4];
    const float* b_f    = (const float*)d_in[5];
    const float* w_i    = (const float*)d_in[6];
    const float* u_i    = (const float*)d_in[7];
    const float* b_i    = (const float*)d_in[8];
    const float* w_o    = (const float*)d_in[9];
    const float* u_o    = (const float*)d_in[10];
    const float* b_o    = (const float*)d_in[11];

    float* outH = (float*)d_out;
    float* outC = outH + (size_t)MROWS * NCOLS;

    // workspace (bf16): Xb 8MB | Hb 8MB | WT0..2 2MB each | UT0..2 2MB each
    char* ws = (char*)d_ws;
    short* Xb  = (short*)(ws);
    short* Hb  = (short*)(ws + (8u << 20));
    short* WT0 = (short*)(ws + (16u << 20));
    short* WT1 = (short*)(ws + (18u << 20));
    short* WT2 = (short*)(ws + (20u << 20));
    short* UT0 = (short*)(ws + (22u << 20));
    short* UT1 = (short*)(ws + (24u << 20));
    short* UT2 = (short*)(ws + (26u << 20));

    // X and H conversion in one launch (2048 blocks each)
    cvt_bf16_kernel<<<4096, 256, 0, stream>>>(inputs, h0, Xb, Hb);

    // all 6 weight transposes in one launch
    W6 p;
    p.src[0] = w_f; p.src[1] = w_i; p.src[2] = w_o;
    p.src[3] = u_f; p.src[4] = u_i; p.src[5] = u_o;
    p.dst[0] = WT0; p.dst[1] = WT1; p.dst[2] = WT2;
    p.dst[3] = UT0; p.dst[4] = UT1; p.dst[5] = UT2;
    transpose_cvt_kernel<<<dim3(32, 32, 6), 256, 0, stream>>>(p);

    dim3 grid(NCOLS / 128, MROWS / 128);   // (8, 32) = 256 blocks
    lstm_gemm_kernel<<<grid, 512, 0, stream>>>(
        Xb, Hb, WT0, WT1, WT2, UT0, UT1, UT2,
        b_f, b_i, b_o, c0, outH, outC);
}

// Round 3
// 77.231 us; speedup vs baseline: 1.4581x; 1.0969x over previous
//
#include <hip/hip_runtime.h>
#include <cstdint>
#include <cstddef>

// ---------------------------------------------------------------------------
// BasicLSTM fused kernel for MI355X (gfx950) — round 3.
//   pre_g = X @ W_g + H @ U_g + b_g   for g in {f, i, o}
//   c_new = sig(pre_f)*c0 + sig(pre_f)*sig(pre_i)     (input_cell == forget!)
//   h_new = sig(pre_o)*tanh(c_new)
// Round-3 changes vs round 2:
//  - T3+T4 deep pipeline: 4 LDS buffers (128 KB), depth-2 prefetch, ONE raw
//    s_barrier per K-step, counted s_waitcnt vmcnt(8) (never 0 in main loop)
//    so 8 global_load_lds stay in flight across every barrier.
//  - T5 setprio(1) around the MFMA cluster (phase role-diversity now exists).
//  Race analysis: single barrier per iter bounds wave drift to <1 iteration;
//  writer targets buf (kt+3)&3 while slowest reader uses buf kt&3 — disjoint.
// ---------------------------------------------------------------------------

typedef __attribute__((ext_vector_type(8))) short bf16x8;
typedef __attribute__((ext_vector_type(4))) float f32x4;
typedef __attribute__((ext_vector_type(8))) short s16x8;
typedef __attribute__((ext_vector_type(4))) float f32x4v;

#define MROWS 4096
#define KDIM  1024   // D == S == 1024
#define NCOLS 1024

__device__ __forceinline__ short f2bf(float f) {
    uint32_t u = __builtin_bit_cast(uint32_t, f);
    u += 0x7fffu + ((u >> 16) & 1u);   // round-to-nearest-even
    return (short)(u >> 16);
}

// ---- fp32 -> bf16 for X and H in one launch (32B in / 16B out per thread) --
__global__ void cvt_bf16_kernel(const float* __restrict__ x,
                                const float* __restrict__ h,
                                short* __restrict__ xb,
                                short* __restrict__ hb) {
    int b = blockIdx.x;
    const float* in;
    short* out;
    if (b < 2048) { in = x; out = xb; }
    else          { in = h; out = hb; b -= 2048; }
    const int i = (b * 256 + threadIdx.x) * 8;
    f32x4v a = *(const f32x4v*)(in + i);
    f32x4v c = *(const f32x4v*)(in + i + 4);
    s16x8 o;
    o[0] = f2bf(a[0]); o[1] = f2bf(a[1]); o[2] = f2bf(a[2]); o[3] = f2bf(a[3]);
    o[4] = f2bf(c[0]); o[5] = f2bf(c[1]); o[6] = f2bf(c[2]); o[7] = f2bf(c[3]);
    *(s16x8*)(out + i) = o;
}

// ---- transpose + convert all 6 weights: w [K][N] fp32 -> wt [N][K] bf16 ----
struct W6 {
    const float* src[6];
    short* dst[6];
};

__global__ void transpose_cvt_kernel(W6 p) {
    __shared__ short tile[32][33];
    const float* __restrict__ w  = p.src[blockIdx.z];
    short* __restrict__       wt = p.dst[blockIdx.z];
    const int tx = threadIdx.x & 31;
    const int ty = threadIdx.x >> 5;          // 0..7
    const int kbase = blockIdx.y * 32;
    const int nbase = blockIdx.x * 32;
#pragma unroll
    for (int r = 0; r < 4; ++r) {
        int k = kbase + ty + r * 8;
        tile[ty + r * 8][tx] = f2bf(w[k * NCOLS + nbase + tx]);
    }
    __syncthreads();
#pragma unroll
    for (int r = 0; r < 4; ++r) {
        int n = nbase + ty + r * 8;
        wt[n * KDIM + kbase + tx] = tile[tx][ty + r * 8];
    }
}

// ---- fused 3-gate GEMM + LSTM cell ----
// Block: 512 threads = 8 waves (2 x 4). Block tile 128x128, 3 gates fused.
// BK = 32, 64 K-steps over [X|H] x [W|U]. 4-deep LDS ring (4 x 32 KB).
// LDS image per tile r (0=A,1..3=B gate): 128 rows x 4 chunks of 16B,
// chunk slot rotated by (row>>1)&3 for conflict-free ds_read_b128.
__global__ __launch_bounds__(512)
void lstm_gemm_kernel(const short* __restrict__ Xb, const short* __restrict__ Hb,
                      const short* __restrict__ WT0, const short* __restrict__ WT1,
                      const short* __restrict__ WT2,
                      const short* __restrict__ UT0, const short* __restrict__ UT1,
                      const short* __restrict__ UT2,
                      const float* __restrict__ bf_, const float* __restrict__ bi_,
                      const float* __restrict__ bo_,
                      const float* __restrict__ c0,
                      float* __restrict__ outH, float* __restrict__ outC) {
    __shared__ __align__(16) short lds[4][16384];   // 4 x 32 KB ring

    const int tid  = threadIdx.x;
    const int lane = tid & 63;
    const int wave = tid >> 6;            // 0..7
    const int wm   = wave >> 2;           // 0..1  (row group)
    const int wn   = wave & 3;            // 0..3  (col group)
    const int m0   = blockIdx.y * 128;
    const int n0   = blockIdx.x * 128;

    const int l15 = lane & 15;
    const int q   = lane >> 4;            // k-chunk index of this lane

    f32x4 acc[3][4][2] = {};   // [gate][m][n]

    // staging: thread tid stages LDS slot tid (16B) of each tile.
    // slot tid = row (tid>>2), chunk-slot (tid&3); it holds global chunk
    // (tid&3) ^ ((row>>1)&3)  -> rotate the global source.
    const int srow   = tid >> 2;                       // 0..127
    const int schunk = (tid & 3) ^ ((tid >> 3) & 3);   // (tid&3)^((srow>>1)&3)
    const int skoff  = schunk * 8;                     // element offset in row

    // precomputed swizzled read byte-offsets within a tile
    int aOff[4], bOff[2];
#pragma unroll
    for (int m = 0; m < 4; ++m) {
        const int row = wm * 64 + m * 16 + l15;
        aOff[m] = row * 64 + ((q ^ ((row >> 1) & 3)) << 4);
    }
#pragma unroll
    for (int n = 0; n < 2; ++n) {
        const int row = wn * 32 + n * 16 + l15;
        bOff[n] = row * 64 + ((q ^ ((row >> 1) & 3)) << 4);
    }

    auto stage = [&](int buf, int kt) {
        const bool second = kt >= 32;
        const short* aS = second ? Hb  : Xb;
        const short* s0 = second ? UT0 : WT0;
        const short* s1 = second ? UT1 : WT1;
        const short* s2 = second ? UT2 : WT2;
        const int kk = (kt & 31) * 32 + skoff;
#pragma unroll
        for (int r = 0; r < 4; ++r) {
            const short* src = (r == 0) ? aS : (r == 1 ? s0 : (r == 2 ? s1 : s2));
            const int rbase = (r == 0) ? m0 : n0;
            const char* g = (const char*)(src + (size_t)(rbase + srow) * KDIM + kk);
            __builtin_amdgcn_global_load_lds(
                (const __attribute__((address_space(1))) unsigned int*)(uintptr_t)g,
                (__attribute__((address_space(3))) unsigned int*)(uintptr_t)
                    ((char*)&lds[buf][0] + r * 8192 + tid * 16),
                16, 0, 0);
        }
    };

    auto compute = [&](int buf) {
        const char* L = (const char*)&lds[buf][0];
        bf16x8 af[4];
#pragma unroll
        for (int m = 0; m < 4; ++m)
            af[m] = *(const bf16x8*)(L + aOff[m]);
        bf16x8 bv[3][2];
#pragma unroll
        for (int g3 = 0; g3 < 3; ++g3)
#pragma unroll
            for (int n = 0; n < 2; ++n)
                bv[g3][n] = *(const bf16x8*)(L + 8192 * (1 + g3) + bOff[n]);
        __builtin_amdgcn_s_setprio(1);
#pragma unroll
        for (int g3 = 0; g3 < 3; ++g3)
#pragma unroll
            for (int n = 0; n < 2; ++n)
#pragma unroll
                for (int m = 0; m < 4; ++m)
                    acc[g3][m][n] = __builtin_amdgcn_mfma_f32_16x16x32_bf16(
                        af[m], bv[g3][n], acc[g3][m][n], 0, 0, 0);
        __builtin_amdgcn_s_setprio(0);
    };

    // prologue: 2 tiles in flight
    stage(0, 0);
    stage(1, 1);

    // main loop: stage kt+2, wait only for tile kt (8 loads stay in flight)
    for (int kt = 0; kt < 62; ++kt) {
        stage((kt + 2) & 3, kt + 2);
        asm volatile("s_waitcnt vmcnt(8)" ::: "memory");
        __builtin_amdgcn_s_barrier();
        __builtin_amdgcn_sched_barrier(0);
        compute(kt & 3);
    }
    // epilogue: drain 4 -> 0
    asm volatile("s_waitcnt vmcnt(4)" ::: "memory");
    __builtin_amdgcn_s_barrier();
    __builtin_amdgcn_sched_barrier(0);
    compute(62 & 3);
    asm volatile("s_waitcnt vmcnt(0)" ::: "memory");
    __builtin_amdgcn_s_barrier();
    __builtin_amdgcn_sched_barrier(0);
    compute(63 & 3);

    // ---- fused LSTM epilogue ----
    const int rj = (lane >> 4) * 4;   // row sub-offset within 16x16 frag
#pragma unroll
    for (int m = 0; m < 4; ++m) {
#pragma unroll
        for (int n = 0; n < 2; ++n) {
            const int col = n0 + wn * 32 + n * 16 + l15;
            const float bfv = bf_[col], biv = bi_[col], bov = bo_[col];
            const f32x4 pf = acc[0][m][n];
            const f32x4 pi = acc[1][m][n];
            const f32x4 po = acc[2][m][n];
#pragma unroll
            for (int j = 0; j < 4; ++j) {
                const int row = m0 + wm * 64 + m * 16 + rj + j;
                const float fg = 1.f / (1.f + __expf(-(pf[j] + bfv)));
                const float ig = 1.f / (1.f + __expf(-(pi[j] + biv)));
                const float og = 1.f / (1.f + __expf(-(po[j] + bov)));
                const float cv = c0[row * NCOLS + col];
                const float cn = fg * cv + fg * ig;   // input_cell == forget gate
                const float e  = __expf(-2.f * cn);
                const float th = (1.f - e) / (1.f + e);
                outH[row * NCOLS + col] = og * th;
                outC[row * NCOLS + col] = cn;
            }
        }
    }
}

extern "C" void kernel_launch(void* const* d_in, const int* in_sizes, int n_in,
                              void* d_out, int out_size, void* d_ws, size_t ws_size,
                              hipStream_t stream) {
    const float* inputs = (const float*)d_in[0];
    const float* h0     = (const float*)d_in[1];
    const float* c0     = (const float*)d_in[2];
    const float* w_f    = (const float*)d_in[3];
    const float* u_f    = (const float*)d_in[4];
    const float* b_f    = (const float*)d_in[5];
    const float* w_i    = (const float*)d_in[6];
    const float* u_i    = (const float*)d_in[7];
    const float* b_i    = (const float*)d_in[8];
    const float* w_o    = (const float*)d_in[9];
    const float* u_o    = (const float*)d_in[10];
    const float* b_o    = (const float*)d_in[11];

    float* outH = (float*)d_out;
    float* outC = outH + (size_t)MROWS * NCOLS;

    // workspace (bf16): Xb 8MB | Hb 8MB | WT0..2 2MB each | UT0..2 2MB each
    char* ws = (char*)d_ws;
    short* Xb  = (short*)(ws);
    short* Hb  = (short*)(ws + (8u << 20));
    short* WT0 = (short*)(ws + (16u << 20));
    short* WT1 = (short*)(ws + (18u << 20));
    short* WT2 = (short*)(ws + (20u << 20));
    short* UT0 = (short*)(ws + (22u << 20));
    short* UT1 = (short*)(ws + (24u << 20));
    short* UT2 = (short*)(ws + (26u << 20));

    // X and H conversion in one launch (2048 blocks each)
    cvt_bf16_kernel<<<4096, 256, 0, stream>>>(inputs, h0, Xb, Hb);

    // all 6 weight transposes in one launch
    W6 p;
    p.src[0] = w_f; p.src[1] = w_i; p.src[2] = w_o;
    p.src[3] = u_f; p.src[4] = u_i; p.src[5] = u_o;
    p.dst[0] = WT0; p.dst[1] = WT1; p.dst[2] = WT2;
    p.dst[3] = UT0; p.dst[4] = UT1; p.dst[5] = UT2;
    transpose_cvt_kernel<<<dim3(32, 32, 6), 256, 0, stream>>>(p);

    dim3 grid(NCOLS / 128, MROWS / 128);   // (8, 32) = 256 blocks
    lstm_gemm_kernel<<<grid, 512, 0, stream>>>(
        Xb, Hb, WT0, WT1, WT2, UT0, UT1, UT2,
        b_f, b_i, b_o, c0, outH, outC);
}

// Round 4
// 76.976 us; speedup vs baseline: 1.4630x; 1.0033x over previous
//
#include <hip/hip_runtime.h>
#include <cstdint>
#include <cstddef>

// ---------------------------------------------------------------------------
// BasicLSTM fused kernel for MI355X (gfx950) — round 4.
//   pre_g = X @ W_g + H @ U_g + b_g   for g in {f, i, o}
//   c_new = sig(pre_f)*c0 + sig(pre_f)*sig(pre_i)     (input_cell == forget!)
//   h_new = sig(pre_o)*tanh(c_new)
// Round-4 changes vs round 3:
//  - Register-level fragment double-buffer: after each barrier, issue the 10
//    ds_read_b128 for tile kt+1 into the alternate reg set, then MFMA(kt) on
//    the current set -> DS pipe and matrix pipe overlap instead of alternate.
//  - Stage depth 3 (stage kt+3), vmcnt(8) retires tile kt+1; 8 loads stay in
//    flight across every barrier (T4).
//  - Ring-4 WAR hazard closed by lgkmcnt(0) before each barrier (reads have a
//    whole MFMA cluster of slack -> near-free drain).
//  - Two-body unrolled main loop: all frag-set indices compile-time static.
// ---------------------------------------------------------------------------

typedef __attribute__((ext_vector_type(8))) short bf16x8;
typedef __attribute__((ext_vector_type(4))) float f32x4;
typedef __attribute__((ext_vector_type(8))) short s16x8;
typedef __attribute__((ext_vector_type(4))) float f32x4v;

#define MROWS 4096
#define KDIM  1024   // D == S == 1024
#define NCOLS 1024

__device__ __forceinline__ short f2bf(float f) {
    uint32_t u = __builtin_bit_cast(uint32_t, f);
    u += 0x7fffu + ((u >> 16) & 1u);   // round-to-nearest-even
    return (short)(u >> 16);
}

// ---- fp32 -> bf16 for X and H in one launch (32B in / 16B out per thread) --
__global__ void cvt_bf16_kernel(const float* __restrict__ x,
                                const float* __restrict__ h,
                                short* __restrict__ xb,
                                short* __restrict__ hb) {
    int b = blockIdx.x;
    const float* in;
    short* out;
    if (b < 2048) { in = x; out = xb; }
    else          { in = h; out = hb; b -= 2048; }
    const int i = (b * 256 + threadIdx.x) * 8;
    f32x4v a = *(const f32x4v*)(in + i);
    f32x4v c = *(const f32x4v*)(in + i + 4);
    s16x8 o;
    o[0] = f2bf(a[0]); o[1] = f2bf(a[1]); o[2] = f2bf(a[2]); o[3] = f2bf(a[3]);
    o[4] = f2bf(c[0]); o[5] = f2bf(c[1]); o[6] = f2bf(c[2]); o[7] = f2bf(c[3]);
    *(s16x8*)(out + i) = o;
}

// ---- transpose + convert all 6 weights: w [K][N] fp32 -> wt [N][K] bf16 ----
struct W6 {
    const float* src[6];
    short* dst[6];
};

__global__ void transpose_cvt_kernel(W6 p) {
    __shared__ short tile[32][33];
    const float* __restrict__ w  = p.src[blockIdx.z];
    short* __restrict__       wt = p.dst[blockIdx.z];
    const int tx = threadIdx.x & 31;
    const int ty = threadIdx.x >> 5;          // 0..7
    const int kbase = blockIdx.y * 32;
    const int nbase = blockIdx.x * 32;
#pragma unroll
    for (int r = 0; r < 4; ++r) {
        int k = kbase + ty + r * 8;
        tile[ty + r * 8][tx] = f2bf(w[k * NCOLS + nbase + tx]);
    }
    __syncthreads();
#pragma unroll
    for (int r = 0; r < 4; ++r) {
        int n = nbase + ty + r * 8;
        wt[n * KDIM + kbase + tx] = tile[tx][ty + r * 8];
    }
}

// ---- fused 3-gate GEMM + LSTM cell ----
// Block: 512 threads = 8 waves (2 x 4). Block tile 128x128, 3 gates fused.
// BK = 32, 64 K-steps over [X|H] x [W|U]. 4-deep LDS ring (4 x 32 KB).
// LDS image per tile r (0=A,1..3=B gate): 128 rows x 4 chunks of 16B,
// chunk slot rotated by (row>>1)&3 for conflict-free ds_read_b128.
__global__ __launch_bounds__(512, 2)
void lstm_gemm_kernel(const short* __restrict__ Xb, const short* __restrict__ Hb,
                      const short* __restrict__ WT0, const short* __restrict__ WT1,
                      const short* __restrict__ WT2,
                      const short* __restrict__ UT0, const short* __restrict__ UT1,
                      const short* __restrict__ UT2,
                      const float* __restrict__ bf_, const float* __restrict__ bi_,
                      const float* __restrict__ bo_,
                      const float* __restrict__ c0,
                      float* __restrict__ outH, float* __restrict__ outC) {
    __shared__ __align__(16) short lds[4][16384];   // 4 x 32 KB ring

    const int tid  = threadIdx.x;
    const int lane = tid & 63;
    const int wave = tid >> 6;            // 0..7
    const int wm   = wave >> 2;           // 0..1  (row group)
    const int wn   = wave & 3;            // 0..3  (col group)
    const int m0   = blockIdx.y * 128;
    const int n0   = blockIdx.x * 128;

    const int l15 = lane & 15;
    const int q   = lane >> 4;            // k-chunk index of this lane

    f32x4 acc[3][4][2] = {};   // [gate][m][n]

    // staging: thread tid stages LDS slot tid (16B) of each tile.
    // slot tid = row (tid>>2), chunk-slot (tid&3); it holds global chunk
    // (tid&3) ^ ((row>>1)&3)  -> rotate the global source.
    const int srow   = tid >> 2;                       // 0..127
    const int schunk = (tid & 3) ^ ((tid >> 3) & 3);   // (tid&3)^((srow>>1)&3)
    const int skoff  = schunk * 8;                     // element offset in row

    // precomputed swizzled read byte-offsets within a tile
    int aOff[4], bOff[2];
#pragma unroll
    for (int m = 0; m < 4; ++m) {
        const int row = wm * 64 + m * 16 + l15;
        aOff[m] = row * 64 + ((q ^ ((row >> 1) & 3)) << 4);
    }
#pragma unroll
    for (int n = 0; n < 2; ++n) {
        const int row = wn * 32 + n * 16 + l15;
        bOff[n] = row * 64 + ((q ^ ((row >> 1) & 3)) << 4);
    }

    auto stage = [&](int buf, int kt) {
        const bool second = kt >= 32;
        const short* aS = second ? Hb  : Xb;
        const short* s0 = second ? UT0 : WT0;
        const short* s1 = second ? UT1 : WT1;
        const short* s2 = second ? UT2 : WT2;
        const int kk = (kt & 31) * 32 + skoff;
#pragma unroll
        for (int r = 0; r < 4; ++r) {
            const short* src = (r == 0) ? aS : (r == 1 ? s0 : (r == 2 ? s1 : s2));
            const int rbase = (r == 0) ? m0 : n0;
            const char* g = (const char*)(src + (size_t)(rbase + srow) * KDIM + kk);
            __builtin_amdgcn_global_load_lds(
                (const __attribute__((address_space(1))) unsigned int*)(uintptr_t)g,
                (__attribute__((address_space(3))) unsigned int*)(uintptr_t)
                    ((char*)&lds[buf][0] + r * 8192 + tid * 16),
                16, 0, 0);
        }
    };

    // fragment register sets (double-buffered, statically indexed)
    bf16x8 fa0[4], fb0[6], fa1[4], fb1[6];

#define READF(FA, FB, BUF)                                                   \
    {                                                                        \
        const char* L_ = (const char*)&lds[(BUF)][0];                        \
        _Pragma("unroll")                                                    \
        for (int m_ = 0; m_ < 4; ++m_)                                       \
            FA[m_] = *(const bf16x8*)(L_ + aOff[m_]);                        \
        _Pragma("unroll")                                                    \
        for (int g_ = 0; g_ < 3; ++g_)                                       \
            _Pragma("unroll")                                                \
            for (int n_ = 0; n_ < 2; ++n_)                                   \
                FB[g_ * 2 + n_] =                                            \
                    *(const bf16x8*)(L_ + 8192 * (1 + g_) + bOff[n_]);       \
    }

#define MFMAC(FA, FB)                                                        \
    {                                                                        \
        __builtin_amdgcn_s_setprio(1);                                       \
        _Pragma("unroll")                                                    \
        for (int g_ = 0; g_ < 3; ++g_)                                       \
            _Pragma("unroll")                                                \
            for (int n_ = 0; n_ < 2; ++n_)                                   \
                _Pragma("unroll")                                            \
                for (int m_ = 0; m_ < 4; ++m_)                               \
                    acc[g_][m_][n_] = __builtin_amdgcn_mfma_f32_16x16x32_bf16(\
                        FA[m_], FB[g_ * 2 + n_], acc[g_][m_][n_], 0, 0, 0);  \
        __builtin_amdgcn_s_setprio(0);                                       \
    }

#define WAITV(N) asm volatile("s_waitcnt vmcnt(" #N ")" ::: "memory")
#define WAITL0   asm volatile("s_waitcnt lgkmcnt(0)" ::: "memory")
#define BAR      __builtin_amdgcn_s_barrier()
#define SCHED0   __builtin_amdgcn_sched_barrier(0)

    // prologue: 3 tiles in flight, frags(0) in set 0
    stage(0, 0);
    stage(1, 1);
    stage(2, 2);
    WAITV(8);          // tile 0 landed (8 = tiles 1,2 in flight)
    BAR;
    SCHED0;
    READF(fa0, fb0, 0);
    WAITL0;            // prologue reads complete before any wave passes kt0 bar

    // main loop: two bodies per iteration (static frag-set indices)
    for (int kt = 0; kt < 60; kt += 2) {
        // body A: MFMA set0(kt), read set1(kt+1)
        stage((kt + 3) & 3, kt + 3);
        WAITV(8);                      // tile kt+1 landed
        BAR;
        SCHED0;
        READF(fa1, fb1, (kt + 1) & 3); // overlaps MFMA below
        MFMAC(fa0, fb0);
        WAITL0;                        // ring WAR safety before next barrier
        // body B: MFMA set1(kt+1), read set0(kt+2)
        stage((kt + 4) & 3, kt + 4);
        WAITV(8);                      // tile kt+2 landed
        BAR;
        SCHED0;
        READF(fa0, fb0, (kt + 2) & 3);
        MFMAC(fa1, fb1);
        WAITL0;
    }

    // epilogue kt = 60..63
    stage(63 & 3, 63);
    WAITV(8);          // tile 61 landed (tiles 62,63 in flight)
    BAR;
    SCHED0;
    READF(fa1, fb1, 61 & 3);
    MFMAC(fa0, fb0);   // kt=60
    WAITL0;

    WAITV(4);          // tile 62 landed
    BAR;
    SCHED0;
    READF(fa0, fb0, 62 & 3);
    MFMAC(fa1, fb1);   // kt=61
    WAITL0;

    WAITV(0);          // tile 63 landed
    BAR;
    SCHED0;
    READF(fa1, fb1, 63 & 3);
    MFMAC(fa0, fb0);   // kt=62
    WAITL0;

    MFMAC(fa1, fb1);   // kt=63

    // ---- fused LSTM epilogue ----
    const int rj = (lane >> 4) * 4;   // row sub-offset within 16x16 frag
#pragma unroll
    for (int m = 0; m < 4; ++m) {
#pragma unroll
        for (int n = 0; n < 2; ++n) {
            const int col = n0 + wn * 32 + n * 16 + l15;
            const float bfv = bf_[col], biv = bi_[col], bov = bo_[col];
            const f32x4 pf = acc[0][m][n];
            const f32x4 pi = acc[1][m][n];
            const f32x4 po = acc[2][m][n];
#pragma unroll
            for (int j = 0; j < 4; ++j) {
                const int row = m0 + wm * 64 + m * 16 + rj + j;
                const float fg = 1.f / (1.f + __expf(-(pf[j] + bfv)));
                const float ig = 1.f / (1.f + __expf(-(pi[j] + biv)));
                const float og = 1.f / (1.f + __expf(-(po[j] + bov)));
                const float cv = c0[row * NCOLS + col];
                const float cn = fg * cv + fg * ig;   // input_cell == forget gate
                const float e  = __expf(-2.f * cn);
                const float th = (1.f - e) / (1.f + e);
                outH[row * NCOLS + col] = og * th;
                outC[row * NCOLS + col] = cn;
            }
        }
    }
#undef READF
#undef MFMAC
#undef WAITV
#undef WAITL0
#undef BAR
#undef SCHED0
}

extern "C" void kernel_launch(void* const* d_in, const int* in_sizes, int n_in,
                              void* d_out, int out_size, void* d_ws, size_t ws_size,
                              hipStream_t stream) {
    const float* inputs = (const float*)d_in[0];
    const float* h0     = (const float*)d_in[1];
    const float* c0     = (const float*)d_in[2];
    const float* w_f    = (const float*)d_in[3];
    const float* u_f    = (const float*)d_in[4];
    const float* b_f    = (const float*)d_in[5];
    const float* w_i    = (const float*)d_in[6];
    const float* u_i    = (const float*)d_in[7];
    const float* b_i    = (const float*)d_in[8];
    const float* w_o    = (const float*)d_in[9];
    const float* u_o    = (const float*)d_in[10];
    const float* b_o    = (const float*)d_in[11];

    float* outH = (float*)d_out;
    float* outC = outH + (size_t)MROWS * NCOLS;

    // workspace (bf16): Xb 8MB | Hb 8MB | WT0..2 2MB each | UT0..2 2MB each
    char* ws = (char*)d_ws;
    short* Xb  = (short*)(ws);
    short* Hb  = (short*)(ws + (8u << 20));
    short* WT0 = (short*)(ws + (16u << 20));
    short* WT1 = (short*)(ws + (18u << 20));
    short* WT2 = (short*)(ws + (20u << 20));
    short* UT0 = (short*)(ws + (22u << 20));
    short* UT1 = (short*)(ws + (24u << 20));
    short* UT2 = (short*)(ws + (26u << 20));

    // X and H conversion in one launch (2048 blocks each)
    cvt_bf16_kernel<<<4096, 256, 0, stream>>>(inputs, h0, Xb, Hb);

    // all 6 weight transposes in one launch
    W6 p;
    p.src[0] = w_f; p.src[1] = w_i; p.src[2] = w_o;
    p.src[3] = u_f; p.src[4] = u_i; p.src[5] = u_o;
    p.dst[0] = WT0; p.dst[1] = WT1; p.dst[2] = WT2;
    p.dst[3] = UT0; p.dst[4] = UT1; p.dst[5] = UT2;
    transpose_cvt_kernel<<<dim3(32, 32, 6), 256, 0, stream>>>(p);

    dim3 grid(NCOLS / 128, MROWS / 128);   // (8, 32) = 256 blocks
    lstm_gemm_kernel<<<grid, 512, 0, stream>>>(
        Xb, Hb, WT0, WT1, WT2, UT0, UT1, UT2,
        b_f, b_i, b_o, c0, outH, outC);
}

// Round 5
// 76.903 us; speedup vs baseline: 1.4644x; 1.0009x over previous
//
#include <hip/hip_runtime.h>
#include <cstdint>
#include <cstddef>

// ---------------------------------------------------------------------------
// BasicLSTM fused kernel for MI355X (gfx950) — round 5.
//   pre_g = X @ W_g + H @ U_g + b_g   for g in {f, i, o}
//   c_new = sig(pre_f)*c0 + sig(pre_f)*sig(pre_i)     (input_cell == forget!)
//   h_new = sig(pre_o)*tanh(c_new)
// Round-5 change vs round 4 (single variable):
//  - sched_barrier(0) BETWEEN READF(next) and MFMAC(cur), and after MFMAC:
//    pins issue order so each wave issues its 10 ds_read_b128 (async) BEFORE
//    the 24-MFMA cluster -> DS pipe drains reads WHILE matrix pipe runs.
//    Round-4 left the order to the scheduler; pipes alternated (sum ~2430
//    cyc/step instead of max ~1000).
// ---------------------------------------------------------------------------

typedef __attribute__((ext_vector_type(8))) short bf16x8;
typedef __attribute__((ext_vector_type(4))) float f32x4;
typedef __attribute__((ext_vector_type(8))) short s16x8;
typedef __attribute__((ext_vector_type(4))) float f32x4v;

#define MROWS 4096
#define KDIM  1024   // D == S == 1024
#define NCOLS 1024

__device__ __forceinline__ short f2bf(float f) {
    uint32_t u = __builtin_bit_cast(uint32_t, f);
    u += 0x7fffu + ((u >> 16) & 1u);   // round-to-nearest-even
    return (short)(u >> 16);
}

// ---- fp32 -> bf16 for X and H in one launch (32B in / 16B out per thread) --
__global__ void cvt_bf16_kernel(const float* __restrict__ x,
                                const float* __restrict__ h,
                                short* __restrict__ xb,
                                short* __restrict__ hb) {
    int b = blockIdx.x;
    const float* in;
    short* out;
    if (b < 2048) { in = x; out = xb; }
    else          { in = h; out = hb; b -= 2048; }
    const int i = (b * 256 + threadIdx.x) * 8;
    f32x4v a = *(const f32x4v*)(in + i);
    f32x4v c = *(const f32x4v*)(in + i + 4);
    s16x8 o;
    o[0] = f2bf(a[0]); o[1] = f2bf(a[1]); o[2] = f2bf(a[2]); o[3] = f2bf(a[3]);
    o[4] = f2bf(c[0]); o[5] = f2bf(c[1]); o[6] = f2bf(c[2]); o[7] = f2bf(c[3]);
    *(s16x8*)(out + i) = o;
}

// ---- transpose + convert all 6 weights: w [K][N] fp32 -> wt [N][K] bf16 ----
struct W6 {
    const float* src[6];
    short* dst[6];
};

__global__ void transpose_cvt_kernel(W6 p) {
    __shared__ short tile[32][33];
    const float* __restrict__ w  = p.src[blockIdx.z];
    short* __restrict__       wt = p.dst[blockIdx.z];
    const int tx = threadIdx.x & 31;
    const int ty = threadIdx.x >> 5;          // 0..7
    const int kbase = blockIdx.y * 32;
    const int nbase = blockIdx.x * 32;
#pragma unroll
    for (int r = 0; r < 4; ++r) {
        int k = kbase + ty + r * 8;
        tile[ty + r * 8][tx] = f2bf(w[k * NCOLS + nbase + tx]);
    }
    __syncthreads();
#pragma unroll
    for (int r = 0; r < 4; ++r) {
        int n = nbase + ty + r * 8;
        wt[n * KDIM + kbase + tx] = tile[tx][ty + r * 8];
    }
}

// ---- fused 3-gate GEMM + LSTM cell ----
// Block: 512 threads = 8 waves (2 x 4). Block tile 128x128, 3 gates fused.
// BK = 32, 64 K-steps over [X|H] x [W|U]. 4-deep LDS ring (4 x 32 KB).
// LDS image per tile r (0=A,1..3=B gate): 128 rows x 4 chunks of 16B,
// chunk slot rotated by (row>>1)&3 for conflict-free ds_read_b128.
__global__ __launch_bounds__(512, 2)
void lstm_gemm_kernel(const short* __restrict__ Xb, const short* __restrict__ Hb,
                      const short* __restrict__ WT0, const short* __restrict__ WT1,
                      const short* __restrict__ WT2,
                      const short* __restrict__ UT0, const short* __restrict__ UT1,
                      const short* __restrict__ UT2,
                      const float* __restrict__ bf_, const float* __restrict__ bi_,
                      const float* __restrict__ bo_,
                      const float* __restrict__ c0,
                      float* __restrict__ outH, float* __restrict__ outC) {
    __shared__ __align__(16) short lds[4][16384];   // 4 x 32 KB ring

    const int tid  = threadIdx.x;
    const int lane = tid & 63;
    const int wave = tid >> 6;            // 0..7
    const int wm   = wave >> 2;           // 0..1  (row group)
    const int wn   = wave & 3;            // 0..3  (col group)
    const int m0   = blockIdx.y * 128;
    const int n0   = blockIdx.x * 128;

    const int l15 = lane & 15;
    const int q   = lane >> 4;            // k-chunk index of this lane

    f32x4 acc[3][4][2] = {};   // [gate][m][n]

    // staging: thread tid stages LDS slot tid (16B) of each tile.
    // slot tid = row (tid>>2), chunk-slot (tid&3); it holds global chunk
    // (tid&3) ^ ((row>>1)&3)  -> rotate the global source.
    const int srow   = tid >> 2;                       // 0..127
    const int schunk = (tid & 3) ^ ((tid >> 3) & 3);   // (tid&3)^((srow>>1)&3)
    const int skoff  = schunk * 8;                     // element offset in row

    // precomputed swizzled read byte-offsets within a tile
    int aOff[4], bOff[2];
#pragma unroll
    for (int m = 0; m < 4; ++m) {
        const int row = wm * 64 + m * 16 + l15;
        aOff[m] = row * 64 + ((q ^ ((row >> 1) & 3)) << 4);
    }
#pragma unroll
    for (int n = 0; n < 2; ++n) {
        const int row = wn * 32 + n * 16 + l15;
        bOff[n] = row * 64 + ((q ^ ((row >> 1) & 3)) << 4);
    }

    auto stage = [&](int buf, int kt) {
        const bool second = kt >= 32;
        const short* aS = second ? Hb  : Xb;
        const short* s0 = second ? UT0 : WT0;
        const short* s1 = second ? UT1 : WT1;
        const short* s2 = second ? UT2 : WT2;
        const int kk = (kt & 31) * 32 + skoff;
#pragma unroll
        for (int r = 0; r < 4; ++r) {
            const short* src = (r == 0) ? aS : (r == 1 ? s0 : (r == 2 ? s1 : s2));
            const int rbase = (r == 0) ? m0 : n0;
            const char* g = (const char*)(src + (size_t)(rbase + srow) * KDIM + kk);
            __builtin_amdgcn_global_load_lds(
                (const __attribute__((address_space(1))) unsigned int*)(uintptr_t)g,
                (__attribute__((address_space(3))) unsigned int*)(uintptr_t)
                    ((char*)&lds[buf][0] + r * 8192 + tid * 16),
                16, 0, 0);
        }
    };

    // fragment register sets (double-buffered, statically indexed)
    bf16x8 fa0[4], fb0[6], fa1[4], fb1[6];

#define READF(FA, FB, BUF)                                                   \
    {                                                                        \
        const char* L_ = (const char*)&lds[(BUF)][0];                        \
        _Pragma("unroll")                                                    \
        for (int m_ = 0; m_ < 4; ++m_)                                       \
            FA[m_] = *(const bf16x8*)(L_ + aOff[m_]);                        \
        _Pragma("unroll")                                                    \
        for (int g_ = 0; g_ < 3; ++g_)                                       \
            _Pragma("unroll")                                                \
            for (int n_ = 0; n_ < 2; ++n_)                                   \
                FB[g_ * 2 + n_] =                                            \
                    *(const bf16x8*)(L_ + 8192 * (1 + g_) + bOff[n_]);       \
    }

#define MFMAC(FA, FB)                                                        \
    {                                                                        \
        __builtin_amdgcn_s_setprio(1);                                       \
        _Pragma("unroll")                                                    \
        for (int g_ = 0; g_ < 3; ++g_)                                       \
            _Pragma("unroll")                                                \
            for (int n_ = 0; n_ < 2; ++n_)                                   \
                _Pragma("unroll")                                            \
                for (int m_ = 0; m_ < 4; ++m_)                               \
                    acc[g_][m_][n_] = __builtin_amdgcn_mfma_f32_16x16x32_bf16(\
                        FA[m_], FB[g_ * 2 + n_], acc[g_][m_][n_], 0, 0, 0);  \
        __builtin_amdgcn_s_setprio(0);                                       \
    }

#define WAITV(N) asm volatile("s_waitcnt vmcnt(" #N ")" ::: "memory")
#define WAITL0   asm volatile("s_waitcnt lgkmcnt(0)" ::: "memory")
#define BAR      __builtin_amdgcn_s_barrier()
#define SCHED0   __builtin_amdgcn_sched_barrier(0)

    // prologue: 3 tiles in flight, frags(0) in set 0
    stage(0, 0);
    stage(1, 1);
    stage(2, 2);
    WAITV(8);          // tile 0 landed (8 = tiles 1,2 in flight)
    BAR;
    SCHED0;
    READF(fa0, fb0, 0);
    WAITL0;            // prologue reads complete before any wave passes kt0 bar

    // main loop: two bodies per iteration (static frag-set indices).
    // Order pinned per half-step: [reads issued] SCHED0 [MFMA cluster] SCHED0
    // [lgkmcnt(0)] -> DS pipe drains reads while matrix pipe runs MFMAs.
    for (int kt = 0; kt < 60; kt += 2) {
        // body A: read set1(kt+1) first, then MFMA set0(kt)
        stage((kt + 3) & 3, kt + 3);
        WAITV(8);                      // tile kt+1 landed
        BAR;
        SCHED0;
        READF(fa1, fb1, (kt + 1) & 3);
        SCHED0;                        // pin: reads issued before MFMA cluster
        MFMAC(fa0, fb0);
        SCHED0;                        // pin: MFMA cluster stays before wait
        WAITL0;                        // ring WAR safety before next barrier
        // body B: read set0(kt+2) first, then MFMA set1(kt+1)
        stage((kt + 4) & 3, kt + 4);
        WAITV(8);                      // tile kt+2 landed
        BAR;
        SCHED0;
        READF(fa0, fb0, (kt + 2) & 3);
        SCHED0;
        MFMAC(fa1, fb1);
        SCHED0;
        WAITL0;
    }

    // epilogue kt = 60..63
    stage(63 & 3, 63);
    WAITV(8);          // tile 61 landed (tiles 62,63 in flight)
    BAR;
    SCHED0;
    READF(fa1, fb1, 61 & 3);
    SCHED0;
    MFMAC(fa0, fb0);   // kt=60
    SCHED0;
    WAITL0;

    WAITV(4);          // tile 62 landed
    BAR;
    SCHED0;
    READF(fa0, fb0, 62 & 3);
    SCHED0;
    MFMAC(fa1, fb1);   // kt=61
    SCHED0;
    WAITL0;

    WAITV(0);          // tile 63 landed
    BAR;
    SCHED0;
    READF(fa1, fb1, 63 & 3);
    SCHED0;
    MFMAC(fa0, fb0);   // kt=62
    SCHED0;
    WAITL0;

    MFMAC(fa1, fb1);   // kt=63

    // ---- fused LSTM epilogue ----
    const int rj = (lane >> 4) * 4;   // row sub-offset within 16x16 frag
#pragma unroll
    for (int m = 0; m < 4; ++m) {
#pragma unroll
        for (int n = 0; n < 2; ++n) {
            const int col = n0 + wn * 32 + n * 16 + l15;
            const float bfv = bf_[col], biv = bi_[col], bov = bo_[col];
            const f32x4 pf = acc[0][m][n];
            const f32x4 pi = acc[1][m][n];
            const f32x4 po = acc[2][m][n];
#pragma unroll
            for (int j = 0; j < 4; ++j) {
                const int row = m0 + wm * 64 + m * 16 + rj + j;
                const float fg = 1.f / (1.f + __expf(-(pf[j] + bfv)));
                const float ig = 1.f / (1.f + __expf(-(pi[j] + biv)));
                const float og = 1.f / (1.f + __expf(-(po[j] + bov)));
                const float cv = c0[row * NCOLS + col];
                const float cn = fg * cv + fg * ig;   // input_cell == forget gate
                const float e  = __expf(-2.f * cn);
                const float th = (1.f - e) / (1.f + e);
                outH[row * NCOLS + col] = og * th;
                outC[row * NCOLS + col] = cn;
            }
        }
    }
#undef READF
#undef MFMAC
#undef WAITV
#undef WAITL0
#undef BAR
#undef SCHED0
}

extern "C" void kernel_launch(void* const* d_in, const int* in_sizes, int n_in,
                              void* d_out, int out_size, void* d_ws, size_t ws_size,
                              hipStream_t stream) {
    const float* inputs = (const float*)d_in[0];
    const float* h0     = (const float*)d_in[1];
    const float* c0     = (const float*)d_in[2];
    const float* w_f    = (const float*)d_in[3];
    const float* u_f    = (const float*)d_in[4];
    const float* b_f    = (const float*)d_in[5];
    const float* w_i    = (const float*)d_in[6];
    const float* u_i    = (const float*)d_in[7];
    const float* b_i    = (const float*)d_in[8];
    const float* w_o    = (const float*)d_in[9];
    const float* u_o    = (const float*)d_in[10];
    const float* b_o    = (const float*)d_in[11];

    float* outH = (float*)d_out;
    float* outC = outH + (size_t)MROWS * NCOLS;

    // workspace (bf16): Xb 8MB | Hb 8MB | WT0..2 2MB each | UT0..2 2MB each
    char* ws = (char*)d_ws;
    short* Xb  = (short*)(ws);
    short* Hb  = (short*)(ws + (8u << 20));
    short* WT0 = (short*)(ws + (16u << 20));
    short* WT1 = (short*)(ws + (18u << 20));
    short* WT2 = (short*)(ws + (20u << 20));
    short* UT0 = (short*)(ws + (22u << 20));
    short* UT1 = (short*)(ws + (24u << 20));
    short* UT2 = (short*)(ws + (26u << 20));

    // X and H conversion in one launch (2048 blocks each)
    cvt_bf16_kernel<<<4096, 256, 0, stream>>>(inputs, h0, Xb, Hb);

    // all 6 weight transposes in one launch
    W6 p;
    p.src[0] = w_f; p.src[1] = w_i; p.src[2] = w_o;
    p.src[3] = u_f; p.src[4] = u_i; p.src[5] = u_o;
    p.dst[0] = WT0; p.dst[1] = WT1; p.dst[2] = WT2;
    p.dst[3] = UT0; p.dst[4] = UT1; p.dst[5] = UT2;
    transpose_cvt_kernel<<<dim3(32, 32, 6), 256, 0, stream>>>(p);

    dim3 grid(NCOLS / 128, MROWS / 128);   // (8, 32) = 256 blocks
    lstm_gemm_kernel<<<grid, 512, 0, stream>>>(
        Xb, Hb, WT0, WT1, WT2, UT0, UT1, UT2,
        b_f, b_i, b_o, c0, outH, outC);
}